// Round 1
// baseline (166.372 us; speedup 1.0000x reference)
//
#include <hip/hip_runtime.h>
#include <math.h>

// WL1 loss over [B=16, C=3, H=512, W=512] fp32.
//   r = sum_c|hr-sr|/255 ; e = sum_c|hr-ema|/255
//   patch_w[b] = (unbiased var of r over sample)^0.2
//   pixel_w = unbiased 3x3 local var of r (reflect pad)
//   loss = mean(|w*sr - w*hr|) = (1/N) sum patch_w * pixel_w * mask * 255*r
//
// R2: latency-bound fix. Grid 1024->2048 blocks (tile 16x128) -> 8 blocks/CU
// = 32 waves/CU (wave cap). hr re-read eliminated: e = sum|hr-ema| computed in
// Stage A from the same hr registers, held in 8 VGPRs via strided-row output
// mapping (thread with row-sub rsub owns output rows {(rsub+7)&7, +8}).
// All global loads now issue before the barrier -> max MLP.

#define BB 16
#define HH 512
#define WW 512
#define HW (HH * WW)
#define CHW (3 * HW)
#define TILE_W 128
#define TILES_PER_BATCH 128  // 32 (h) x 4 (w)
#define NBLOCKS (BB * TILES_PER_BATCH)
#define LDS_STRIDE 136  // col 3 = left halo, 4..131 = centers, 132 = right halo, 133-135 slack

__device__ __forceinline__ int reflect_h(int gh) {
  gh = gh < 0 ? -gh : gh;
  return gh >= HH ? 2 * HH - 2 - gh : gh;
}

__global__ __launch_bounds__(256, 8) void wl1_main(
    const float* __restrict__ sr, const float* __restrict__ srema,
    const float* __restrict__ hr,
    float* __restrict__ p_sum, float* __restrict__ p_sum2,
    float* __restrict__ p_loss) {
  __shared__ float rt[18][LDS_STRIDE];
  const int bid = blockIdx.x;
  const int b = bid >> 7;
  const int t = bid & 127;
  const int h0 = (t >> 2) << 4;    // 0,16,...,496
  const int w0 = (t & 3) << 7;     // 0,128,256,384
  const int tid = threadIdx.x;
  const int c4 = tid & 31;         // float4 column group (0..31)
  const int rsub = tid >> 5;       // row-sub (0..7)
  const int ob = (rsub + 7) & 7;   // base output row owned by this thread
  const float* __restrict__ srb = sr + (size_t)b * CHW;
  const float* __restrict__ hrb = hr + (size_t)b * CHW;
  const float* __restrict__ eb = srema + (size_t)b * CHW;

  // Stage A: 18 halo rows of r -> LDS; e for this thread's 2 output rows -> regs.
  // Rows it*8+rsub: rsub>=1 sees its e-rows at it=0,1; rsub==0 at it=1,2.
  float e0[4] = {0.f, 0.f, 0.f, 0.f};  // e for output row ob
  float e1[4] = {0.f, 0.f, 0.f, 0.f};  // e for output row ob+8
#pragma unroll
  for (int it = 0; it < 3; ++it) {
    const int row = it * 8 + rsub;
    if (row < 18) {
      const int gh = reflect_h(h0 - 1 + row);
      const float* hb = hrb + gh * WW + w0 + 4 * c4;
      const float* sb = srb + gh * WW + w0 + 4 * c4;
      float4 ha = *(const float4*)(hb);
      float4 hbv = *(const float4*)(hb + HW);
      float4 hc = *(const float4*)(hb + 2 * HW);
      float4 sa = *(const float4*)(sb);
      float4 sbv = *(const float4*)(sb + HW);
      float4 sc = *(const float4*)(sb + 2 * HW);
      float4 r4;
      r4.x = (fabsf(ha.x - sa.x) + fabsf(hbv.x - sbv.x) + fabsf(hc.x - sc.x)) / 255.0f;
      r4.y = (fabsf(ha.y - sa.y) + fabsf(hbv.y - sbv.y) + fabsf(hc.y - sc.y)) / 255.0f;
      r4.z = (fabsf(ha.z - sa.z) + fabsf(hbv.z - sbv.z) + fabsf(hc.z - sc.z)) / 255.0f;
      r4.w = (fabsf(ha.w - sa.w) + fabsf(hbv.w - sbv.w) + fabsf(hc.w - sc.w)) / 255.0f;
      *(float4*)&rt[row][4 + 4 * c4] = r4;
      const int orow = row - 1;  // output row this LDS row centers
      if (orow >= 0 && orow < 16) {
        // gh == h0 + orow here (in range, no reflect)
        const float* ep = eb + gh * WW + w0 + 4 * c4;
        float4 ea = *(const float4*)(ep);
        float4 eb2 = *(const float4*)(ep + HW);
        float4 ec = *(const float4*)(ep + 2 * HW);
        float ex = (fabsf(ha.x - ea.x) + fabsf(hbv.x - eb2.x) + fabsf(hc.x - ec.x)) / 255.0f;
        float ey = (fabsf(ha.y - ea.y) + fabsf(hbv.y - eb2.y) + fabsf(hc.y - ec.y)) / 255.0f;
        float ez = (fabsf(ha.z - ea.z) + fabsf(hbv.z - eb2.z) + fabsf(hc.z - ec.z)) / 255.0f;
        float ew = (fabsf(ha.w - ea.w) + fabsf(hbv.w - eb2.w) + fabsf(hc.w - ec.w)) / 255.0f;
        if (orow == ob) {
          e0[0] = ex; e0[1] = ey; e0[2] = ez; e0[3] = ew;
        } else {
          e1[0] = ex; e1[1] = ey; e1[2] = ez; e1[3] = ew;
        }
      }
    }
  }
  // Stage A2: left/right halo columns (36 scalar items)
  if (tid < 36) {
    int row = tid >> 1, side = tid & 1;
    int gh = reflect_h(h0 - 1 + row);
    int gw = side ? w0 + TILE_W : w0 - 1;
    if (gw < 0) gw = 1;
    if (gw > 511) gw = 1022 - gw;
    int base = gh * WW + gw;
    float v = (fabsf(hrb[base] - srb[base]) +
               fabsf(hrb[base + HW] - srb[base + HW]) +
               fabsf(hrb[base + 2 * HW] - srb[base + 2 * HW])) /
              255.0f;
    rt[row][side ? 4 + TILE_W : 3] = v;
  }
  __syncthreads();

  // Stage B: 2 output rows (ob, ob+8) x 4 cols per thread, pure LDS+VALU.
  float v1 = 0.f, v2 = 0.f, v3 = 0.f;
#pragma unroll
  for (int rr = 0; rr < 2; ++rr) {
    const int orow = ob + rr * 8;  // LDS center row = orow+1
    float cs[6] = {0, 0, 0, 0, 0, 0}, cq[6] = {0, 0, 0, 0, 0, 0};
    float center[4];
#pragma unroll
    for (int dr = 0; dr < 3; ++dr) {
      const float* lp = &rt[orow + dr][4 * c4];
      float4 a = *(const float4*)(lp);
      float4 bq = *(const float4*)(lp + 4);
      float4 cq4 = *(const float4*)(lp + 8);
      float f3 = a.w, f4 = bq.x, f5 = bq.y, f6 = bq.z, f7 = bq.w, f8 = cq4.x;
      cs[0] += f3; cq[0] += f3 * f3;
      cs[1] += f4; cq[1] += f4 * f4;
      cs[2] += f5; cq[2] += f5 * f5;
      cs[3] += f6; cq[3] += f6 * f6;
      cs[4] += f7; cq[4] += f7 * f7;
      cs[5] += f8; cq[5] += f8 * f8;
      if (dr == 1) { center[0] = f4; center[1] = f5; center[2] = f6; center[3] = f7; }
    }
    const float* e4 = rr ? e1 : e0;
#pragma unroll
    for (int cc = 0; cc < 4; ++cc) {
      float s = cs[cc] + cs[cc + 1] + cs[cc + 2];
      float q = cq[cc] + cq[cc + 1] + cq[cc + 2];
      float pvar = (q - s * s / 9.0f) / 8.0f;
      float rc = center[cc];
      v1 += rc;
      v2 += rc * rc;
      if (rc >= e4[cc]) v3 += pvar * (255.0f * rc);
    }
  }

  // block reduce (4 waves)
#pragma unroll
  for (int off = 32; off > 0; off >>= 1) {
    v1 += __shfl_down(v1, off, 64);
    v2 += __shfl_down(v2, off, 64);
    v3 += __shfl_down(v3, off, 64);
  }
  __shared__ float red[3][4];
  const int wv = tid >> 6;
  if ((tid & 63) == 0) {
    red[0][wv] = v1;
    red[1][wv] = v2;
    red[2][wv] = v3;
  }
  __syncthreads();
  if (tid == 0) {
    p_sum[bid] = red[0][0] + red[0][1] + red[0][2] + red[0][3];
    p_sum2[bid] = red[1][0] + red[1][1] + red[1][2] + red[1][3];
    p_loss[bid] = red[2][0] + red[2][1] + red[2][2] + red[2][3];
  }
}

// Single fused reduction: wave w handles batch w (128 partials each, 2/lane).
__global__ __launch_bounds__(1024) void wl1_reduce(
    const float* __restrict__ p_sum, const float* __restrict__ p_sum2,
    const float* __restrict__ p_loss, float* __restrict__ out) {
  const int tid = threadIdx.x;
  const int b = tid >> 6, k = tid & 63;
  const int i = b * TILES_PER_BATCH + k;
  double s = (double)p_sum[i] + (double)p_sum[i + 64];
  double s2 = (double)p_sum2[i] + (double)p_sum2[i + 64];
  double sl = (double)p_loss[i] + (double)p_loss[i + 64];
#pragma unroll
  for (int off = 32; off > 0; off >>= 1) {
    s += __shfl_down(s, off, 64);
    s2 += __shfl_down(s2, off, 64);
    sl += __shfl_down(sl, off, 64);
  }
  __shared__ double acc[BB];
  if (k == 0) {
    const double n = (double)HW;
    double var = (s2 - s * s / n) / (n - 1.0);
    acc[b] = pow(var, 0.2) * sl;
  }
  __syncthreads();
  if (tid == 0) {
    double tot = 0.0;
#pragma unroll
    for (int j = 0; j < BB; ++j) tot += acc[j];
    out[0] = (float)(tot / (double)((size_t)BB * CHW));
  }
}

extern "C" void kernel_launch(void* const* d_in, const int* in_sizes, int n_in,
                              void* d_out, int out_size, void* d_ws,
                              size_t ws_size, hipStream_t stream) {
  const float* sr = (const float*)d_in[0];
  const float* srema = (const float*)d_in[1];
  const float* hr = (const float*)d_in[2];
  float* out = (float*)d_out;

  float* p_sum = (float*)d_ws;
  float* p_sum2 = p_sum + NBLOCKS;
  float* p_loss = p_sum2 + NBLOCKS;

  wl1_main<<<NBLOCKS, 256, 0, stream>>>(sr, srema, hr, p_sum, p_sum2, p_loss);
  wl1_reduce<<<1, 1024, 0, stream>>>(p_sum, p_sum2, p_loss, out);
}